// Round 1
// baseline (446.860 us; speedup 1.0000x reference)
//
#include <hip/hip_runtime.h>
#include <stdint.h>

typedef __attribute__((ext_vector_type(4))) float f32x4;
typedef __attribute__((ext_vector_type(8))) short short8;

#define MFMA16(a, b, c) __builtin_amdgcn_mfma_f32_16x16x32_bf16((a), (b), (c), 0, 0, 0)

__device__ __forceinline__ unsigned short f2bf(float f) {
  unsigned int x = __float_as_uint(f);
  return (unsigned short)((x + 0x7fffu + ((x >> 16) & 1u)) >> 16);
}

// load 8 elements as bf16 (converting f32 -> bf16 RNE if needed), store 16B to dst
__device__ __forceinline__ void load8cv(const float* __restrict__ s, void* d) {
  const f32x4* p = (const f32x4*)s;
  f32x4 a = p[0], b = p[1];
  short8 t;
  t[0] = (short)f2bf(a[0]); t[1] = (short)f2bf(a[1]);
  t[2] = (short)f2bf(a[2]); t[3] = (short)f2bf(a[3]);
  t[4] = (short)f2bf(b[0]); t[5] = (short)f2bf(b[1]);
  t[6] = (short)f2bf(b[2]); t[7] = (short)f2bf(b[3]);
  *(short8*)d = t;
}
__device__ __forceinline__ void load8cv(const unsigned short* __restrict__ s, void* d) {
  *(short8*)d = *(const short8*)s;
}

__device__ __forceinline__ void storec(float* p, float v) { *p = v; }
__device__ __forceinline__ void storec(unsigned short* p, float v) { *p = f2bf(v); }

// ---------------------------------------------------------------------------
// C[M][N] = A[M][K] @ Bt[N][K]^T + bias   (nn.Linear). A: f32 or bf16(ushort),
// Bt: f32 weights. Output bf16 or f32. 128x128 tile, BK=32, 4 waves (2x2),
// each wave 4x4 frags of 16x16x32. LDS stride padded to 40 elems (80B) so
// frag ds_read_b128 is conflict-free.
// ---------------------------------------------------------------------------
template <typename TA, typename TOUT>
__global__ __launch_bounds__(256) void gemm_bias(const TA* __restrict__ A,
                                                 const float* __restrict__ Bt,
                                                 const float* __restrict__ bias,
                                                 TOUT* __restrict__ C,
                                                 int M, int N, int K) {
  constexpr int AST = 40;  // padded LDS stride (elems)
  __shared__ unsigned short As[128 * AST];
  __shared__ unsigned short Bs[128 * AST];
  const int tid = threadIdx.x;
  const int lane = tid & 63;
  const int wv = tid >> 6;
  const int g = lane >> 4, r = lane & 15;
  const int wm = wv >> 1, wn = wv & 1;
  const int m0 = blockIdx.y * 128, n0 = blockIdx.x * 128;

  f32x4 acc[4][4];
#pragma unroll
  for (int m = 0; m < 4; ++m)
#pragma unroll
    for (int n = 0; n < 4; ++n) acc[m][n] = (f32x4){0.f, 0.f, 0.f, 0.f};

  for (int k0 = 0; k0 < K; k0 += 32) {
    __syncthreads();
#pragma unroll
    for (int cc = 0; cc < 2; ++cc) {
      int chunk = tid + cc * 256;        // 0..511
      int row = chunk >> 2;              // 0..127
      int kc = (chunk & 3) * 8;          // 0,8,16,24
      load8cv(A + (size_t)(m0 + row) * K + k0 + kc, &As[row * AST + kc]);
      load8cv(Bt + (size_t)(n0 + row) * K + k0 + kc, &Bs[row * AST + kc]);
    }
    __syncthreads();
    short8 af[4], bf[4];
#pragma unroll
    for (int m = 0; m < 4; ++m)
      af[m] = *(const short8*)&As[(wm * 64 + m * 16 + r) * AST + g * 8];
#pragma unroll
    for (int n = 0; n < 4; ++n)
      bf[n] = *(const short8*)&Bs[(wn * 64 + n * 16 + r) * AST + g * 8];
#pragma unroll
    for (int m = 0; m < 4; ++m)
#pragma unroll
      for (int n = 0; n < 4; ++n) acc[m][n] = MFMA16(af[m], bf[n], acc[m][n]);
  }

#pragma unroll
  for (int n = 0; n < 4; ++n) {
    int col = n0 + wn * 64 + n * 16 + r;
    float bv = bias[col];
#pragma unroll
    for (int m = 0; m < 4; ++m) {
#pragma unroll
      for (int i = 0; i < 4; ++i) {
        int rowg = m0 + wm * 64 + m * 16 + 4 * g + i;
        storec(C + (size_t)rowg * N + col, acc[m][n][i] + bv);
      }
    }
  }
}

// ---------------------------------------------------------------------------
// V16[b*2048+s][h*64+d] -> Vt[(b*16+h)*64+d][s]  (bf16). d fastest across
// lanes => coalesced 128B reads; 16B writes complete lines via L2.
// ---------------------------------------------------------------------------
__global__ __launch_bounds__(256) void transpose_v(const unsigned short* __restrict__ V,
                                                   unsigned short* __restrict__ Vt) {
  int t = blockIdx.x * 256 + threadIdx.x;  // 524288 total
  int d = t & 63;
  int sc = (t >> 6) & 255;
  int bh = t >> 14;  // 0..31
  int b = bh >> 4, h = bh & 15;
  unsigned short vals[8];
#pragma unroll
  for (int j = 0; j < 8; ++j)
    vals[j] = V[(size_t)(b * 2048 + sc * 8 + j) * 1024 + h * 64 + d];
  *(short8*)&Vt[((size_t)bh * 64 + d) * 2048 + sc * 8] = *(short8*)vals;
}

// ---------------------------------------------------------------------------
// Fused attention. Block: 4 waves x 16 q-rows = 64 q-rows of one (b,h).
// Pass 1: exact row max & sum (online, scores recomputed later).
// Pass 2: recompute scores, write softmax to attn (f32), PV via MFMA.
// LDS tiles XOR-swizzled: byte ^= (row&7)<<4 (rows are 128B).
// ---------------------------------------------------------------------------
__global__ __launch_bounds__(256) void attn_fused(const unsigned short* __restrict__ Q,
                                                  const unsigned short* __restrict__ K,
                                                  const unsigned short* __restrict__ Vt,
                                                  float* __restrict__ attn,
                                                  unsigned short* __restrict__ O) {
  __shared__ unsigned short kbuf[64 * 64];
  __shared__ unsigned short vbuf[64 * 64];
  __shared__ unsigned short pbuf[4][16 * 64];

  const int tid = threadIdx.x;
  const int lane = tid & 63;
  const int wv = tid >> 6;
  const int g = lane >> 4, r = lane & 15;
  const int qt = blockIdx.x, h = blockIdx.y, b = blockIdx.z;
  const int qloc = qt * 64 + wv * 16;        // q row within (b,h)
  const int qrow0 = b * 2048 + qloc;         // row in [4096] layout
  const unsigned short* Kbh = K + (size_t)b * 2048 * 1024 + h * 64;
  const unsigned short* Vbh = Vt + (size_t)(b * 16 + h) * 64 * 2048;
  float* attn_bh = attn + (size_t)(b * 16 + h) * 2048 * 2048;

  short8 qf[2];
#pragma unroll
  for (int kk = 0; kk < 2; ++kk)
    qf[kk] = *(const short8*)&Q[(size_t)(qrow0 + r) * 1024 + h * 64 + kk * 32 + g * 8];

  float mrow[4], lrow[4];
#pragma unroll
  for (int i = 0; i < 4; ++i) { mrow[i] = -3.0e38f; lrow[i] = 0.f; }

  // ---------------- pass 1: row max & sum ----------------
  for (int kt = 0; kt < 2048; kt += 64) {
    __syncthreads();
    for (int c = tid; c < 512; c += 256) {
      int kr = c >> 3, c8 = (c & 7) * 8;
      short8 v = *(const short8*)&Kbh[(size_t)(kt + kr) * 1024 + c8];
      *(short8*)((char*)kbuf + ((kr * 128 + c8 * 2) ^ ((kr & 7) << 4))) = v;
    }
    __syncthreads();
    f32x4 s[4];
#pragma unroll
    for (int ct = 0; ct < 4; ++ct) {
      s[ct] = (f32x4){0.f, 0.f, 0.f, 0.f};
      int row = ct * 16 + r;
#pragma unroll
      for (int kk = 0; kk < 2; ++kk) {
        short8 kf = *(const short8*)((const char*)kbuf +
                     ((row * 128 + (kk * 32 + g * 8) * 2) ^ ((row & 7) << 4)));
        s[ct] = MFMA16(qf[kk], kf, s[ct]);
      }
      s[ct] = s[ct] * 0.125f;  // SCALE = 1/sqrt(64)
    }
    float mx[4], se[4];
#pragma unroll
    for (int i = 0; i < 4; ++i) {
      mx[i] = fmaxf(fmaxf(s[0][i], s[1][i]), fmaxf(s[2][i], s[3][i]));
      mx[i] = fmaxf(mx[i], __shfl_xor(mx[i], 1));
      mx[i] = fmaxf(mx[i], __shfl_xor(mx[i], 2));
      mx[i] = fmaxf(mx[i], __shfl_xor(mx[i], 4));
      mx[i] = fmaxf(mx[i], __shfl_xor(mx[i], 8));
    }
#pragma unroll
    for (int i = 0; i < 4; ++i) {
      float mn = fmaxf(mrow[i], mx[i]);
      se[i] = __expf(s[0][i] - mn) + __expf(s[1][i] - mn) +
              __expf(s[2][i] - mn) + __expf(s[3][i] - mn);
      lrow[i] = lrow[i] * __expf(mrow[i] - mn);
      mrow[i] = mn;
      se[i] += __shfl_xor(se[i], 1);
      se[i] += __shfl_xor(se[i], 2);
      se[i] += __shfl_xor(se[i], 4);
      se[i] += __shfl_xor(se[i], 8);
      lrow[i] += se[i];
    }
  }
  float linv[4];
#pragma unroll
  for (int i = 0; i < 4; ++i) linv[i] = 1.0f / lrow[i];

  // ---------------- pass 2: write attention + PV ----------------
  f32x4 oacc[4];
#pragma unroll
  for (int i = 0; i < 4; ++i) oacc[i] = (f32x4){0.f, 0.f, 0.f, 0.f};
  unsigned short* pb = &pbuf[wv][0];

  for (int kt = 0; kt < 2048; kt += 64) {
    __syncthreads();
    for (int c = tid; c < 512; c += 256) {
      int kr = c >> 3, c8 = (c & 7) * 8;
      short8 v = *(const short8*)&Kbh[(size_t)(kt + kr) * 1024 + c8];
      *(short8*)((char*)kbuf + ((kr * 128 + c8 * 2) ^ ((kr & 7) << 4))) = v;
      short8 w = *(const short8*)&Vbh[(size_t)kr * 2048 + kt + c8];
      *(short8*)((char*)vbuf + ((kr * 128 + c8 * 2) ^ ((kr & 7) << 4))) = w;
    }
    __syncthreads();
    f32x4 s[4];
#pragma unroll
    for (int ct = 0; ct < 4; ++ct) {
      s[ct] = (f32x4){0.f, 0.f, 0.f, 0.f};
      int row = ct * 16 + r;
#pragma unroll
      for (int kk = 0; kk < 2; ++kk) {
        short8 kf = *(const short8*)((const char*)kbuf +
                     ((row * 128 + (kk * 32 + g * 8) * 2) ^ ((row & 7) << 4)));
        s[ct] = MFMA16(qf[kk], kf, s[ct]);
      }
      s[ct] = s[ct] * 0.125f;
    }
    // p = exp(s-m)/l ; write attention f32 ; stash bf16 P for the PV MFMA
#pragma unroll
    for (int ct = 0; ct < 4; ++ct) {
#pragma unroll
      for (int i = 0; i < 4; ++i) {
        float p = __expf(s[ct][i] - mrow[i]) * linv[i];
        int qr = qloc + 4 * g + i;
        attn_bh[(size_t)qr * 2048 + kt + ct * 16 + r] = p;
        int prow = 4 * g + i, pcol = ct * 16 + r;
        *(unsigned short*)((char*)pb + ((prow * 128 + pcol * 2) ^ ((prow & 7) << 4))) = f2bf(p);
      }
    }
    // PV: O[16q x 64d] += P[16x64] @ V[64x64]
#pragma unroll
    for (int kk2 = 0; kk2 < 2; ++kk2) {
      short8 pa = *(const short8*)((const char*)pb +
                   ((r * 128 + (kk2 * 32 + g * 8) * 2) ^ ((r & 7) << 4)));
#pragma unroll
      for (int ct2 = 0; ct2 < 4; ++ct2) {
        int vrow = ct2 * 16 + r;
        short8 vf = *(const short8*)((const char*)vbuf +
                     ((vrow * 128 + (kk2 * 32 + g * 8) * 2) ^ ((vrow & 7) << 4)));
        oacc[ct2] = MFMA16(pa, vf, oacc[ct2]);
      }
    }
  }
  // epilogue: O rows qloc+4g+i, cols h*64 + ct2*16 + r
#pragma unroll
  for (int ct2 = 0; ct2 < 4; ++ct2)
#pragma unroll
    for (int i = 0; i < 4; ++i)
      O[(size_t)(qrow0 + 4 * g + i) * 1024 + h * 64 + ct2 * 16 + r] = f2bf(oacc[ct2][i]);
}

// ---------------------------------------------------------------------------
extern "C" void kernel_launch(void* const* d_in, const int* in_sizes, int n_in,
                              void* d_out, int out_size, void* d_ws, size_t ws_size,
                              hipStream_t stream) {
  const float* q_in = (const float*)d_in[0];
  const float* k_in = (const float*)d_in[1];
  const float* v_in = (const float*)d_in[2];
  const float* wq = (const float*)d_in[3];
  const float* bq = (const float*)d_in[4];
  const float* wk = (const float*)d_in[5];
  const float* bk = (const float*)d_in[6];
  const float* wv = (const float*)d_in[7];
  const float* bv = (const float*)d_in[8];
  const float* wo = (const float*)d_in[9];
  const float* bo = (const float*)d_in[10];

  char* ws = (char*)d_ws;
  const size_t MB8 = 8ull * 1024 * 1024;
  unsigned short* Q16 = (unsigned short*)(ws);
  unsigned short* K16 = (unsigned short*)(ws + MB8);
  unsigned short* V16 = (unsigned short*)(ws + 2 * MB8);
  unsigned short* Vt  = (unsigned short*)(ws + 3 * MB8);
  unsigned short* O16 = (unsigned short*)(ws + 4 * MB8);

  float* out = (float*)d_out;
  float* attn = out + 4194304ull;  // out[B,S,D] then attention[B,H,S,S]

  dim3 blk(256);
  dim3 gproj(8, 32);  // N/128 x M/128
  gemm_bias<float, unsigned short><<<gproj, blk, 0, stream>>>(q_in, wq, bq, Q16, 4096, 1024, 1024);
  gemm_bias<float, unsigned short><<<gproj, blk, 0, stream>>>(k_in, wk, bk, K16, 4096, 1024, 1024);
  gemm_bias<float, unsigned short><<<gproj, blk, 0, stream>>>(v_in, wv, bv, V16, 4096, 1024, 1024);
  transpose_v<<<dim3(2048), blk, 0, stream>>>(V16, Vt);
  attn_fused<<<dim3(32, 16, 2), blk, 0, stream>>>(Q16, K16, Vt, attn, O16);
  gemm_bias<unsigned short, float><<<gproj, blk, 0, stream>>>(O16, wo, bo, out, 4096, 1024, 1024);
}